// Round 10
// baseline (361.966 us; speedup 1.0000x reference)
//
#include <hip/hip_runtime.h>
#include <hip/hip_bf16.h>
#include <stdint.h>

#define S_LEN 1024
#define D_MODEL 4096
#define NHEAD 32
#define NKV 8
#define HD 128
#define CACHE_T 1024
#define T_TOT 2048
#define NQKV 6144
#define QSCALE 0.08838834764831845f

typedef __attribute__((ext_vector_type(8))) short short8;
typedef __attribute__((ext_vector_type(4))) float floatx4;
typedef __attribute__((ext_vector_type(16))) float floatx16;

__device__ __forceinline__ unsigned short f2bf(float f) {
  union { float f; uint32_t u; } v; v.f = f;
  uint32_t r = v.u + 0x7FFFu + ((v.u >> 16) & 1u);
  return (unsigned short)(r >> 16);
}

__device__ __forceinline__ unsigned pack2bf(float a, float b) {
  union { __hip_bfloat162 h2; unsigned u; } c;
  c.h2 = __float22bfloat162_rn(make_float2(a, b));
  return c.u;
}

__device__ __forceinline__ void gload_lds16(const void* g, void* s) {
  __builtin_amdgcn_global_load_lds((const __attribute__((address_space(1))) void*)g,
                                   (__attribute__((address_space(3))) void*)s, 16, 0, 0);
}

// ---------------------------------------------------------------- generic fp32 -> bf16 (n8 = count/8)
__global__ void convf2b_kernel(const float* __restrict__ in, unsigned short* __restrict__ out, int n8) {
  int stride = gridDim.x * blockDim.x;
  for (int t = blockIdx.x * blockDim.x + threadIdx.x; t < n8; t += stride) {
    int i = t * 8;
    floatx4 a = *(const floatx4*)(in + i);
    floatx4 b = *(const floatx4*)(in + i + 4);
    short8 o;
    o[0] = (short)f2bf(a[0]); o[1] = (short)f2bf(a[1]); o[2] = (short)f2bf(a[2]); o[3] = (short)f2bf(a[3]);
    o[4] = (short)f2bf(b[0]); o[5] = (short)f2bf(b[1]); o[6] = (short)f2bf(b[2]); o[7] = (short)f2bf(b[3]);
    *(short8*)(out + i) = o;
  }
}

// ---------------------------------------------------------------- mask nonzero flag
__global__ void mask_flag_kernel(const float* __restrict__ m, int n, int* __restrict__ flag) {
  int stride = gridDim.x * blockDim.x;
  bool nz = false;
  for (int i = blockIdx.x * blockDim.x + threadIdx.x; i < n; i += stride)
    nz |= (m[i] != 0.0f);
  if (nz) atomicOr(flag, 1);
}

// ---------------------------------------------------------------- fused fp32-W GEMM, DMA-to-LDS + fragment-time cvt
// C(MxN fp32) = A(MxK bf16) * W^T; W fp32 rows (W0/W1/W2 split at n1/n2).
// W staged as fp32 via global_load_lds (fire-and-forget); bf16 conversion happens
// at fragment-read time (2x ds_read_b128 + 4x v_cvt_pk per fragment).
__global__ __launch_bounds__(256, 2)
void gemm_fw2_kernel(const unsigned short* __restrict__ A,
                     const float* __restrict__ W0, const float* __restrict__ W1, const float* __restrict__ W2,
                     int n1, int n2,
                     float* __restrict__ C,
                     int M, int N, int K, int ldc, int GM)
{
  __shared__ __align__(16) unsigned char As[2][64 * 128];    // bf16 A, 8 KB x2
  __shared__ __align__(16) unsigned char Wf[2][128 * 256];   // fp32 W, 32 KB x2 -> 80 KB total

  const int nwg = gridDim.x;
  int orig = blockIdx.x;
  int wg = (orig & 7) * (nwg >> 3) + (orig >> 3);
  const int mt = wg % GM, nt = wg / GM;
  const int m0 = mt * 64, n0 = nt * 128;

  const int tid = threadIdx.x;
  const int wid = tid >> 6, lane = tid & 63;
  const int g4 = lane >> 4, r16 = lane & 15;
  const int wr = (wid >> 1) * 32, wc = (wid & 1) * 64;

  // A staging: pre-swizzled global source, linear LDS dest (verified layout)
  const int lr = lane >> 3, lc = lane & 7;
  const unsigned short* Arow[2];
#pragma unroll
  for (int i = 0; i < 2; ++i) {
    int r = (wid * 2 + i) * 8 + lr;
    Arow[i] = A + (size_t)(m0 + r) * K + (lc ^ (r & 7)) * 8;
  }

  // W fp32 staging: instr j covers rows j*16..j*16+15; this thread: row j*16+(tid>>4),
  // 16B chunk position pos=tid&15 holds global chunk (pos ^ (row&15))  [G21 involution]
  const float* Wsrc[8];
#pragma unroll
  for (int j = 0; j < 8; ++j) {
    int r = j * 16 + (tid >> 4);
    int pos = tid & 15;
    int ng = n0 + r;
    const float* p = (ng < n1) ? (W0 + (size_t)ng * K)
                   : (ng < n2) ? (W1 + (size_t)(ng - n1) * K)
                               : (W2 + (size_t)(ng - n2) * K);
    Wsrc[j] = p + (pos ^ (r & 15)) * 4;
  }

  auto stage = [&](int buf, int kt) {
    const int kb = kt * 64;
#pragma unroll
    for (int i = 0; i < 2; ++i)
      gload_lds16(Arow[i] + kb, &As[buf][(wid * 2 + i) * 1024]);
#pragma unroll
    for (int j = 0; j < 8; ++j)
      gload_lds16(Wsrc[j] + kb, &Wf[buf][j * 4096 + tid * 16]);
  };

  floatx4 acc[2][4];
#pragma unroll
  for (int m = 0; m < 2; ++m)
#pragma unroll
    for (int n = 0; n < 4; ++n) acc[m][n] = (floatx4){0.f, 0.f, 0.f, 0.f};

  const int NK = K >> 6;
  stage(0, 0);
  __syncthreads();
  int cur = 0;
  for (int kt = 0; kt < NK; ++kt) {
    if (kt + 1 < NK) stage(cur ^ 1, kt + 1);
#pragma unroll
    for (int kk = 0; kk < 2; ++kk) {
      short8 af[2], bf[4];
#pragma unroll
      for (int m = 0; m < 2; ++m) {
        int row = wr + m * 16 + r16;
        af[m] = *(const short8*)(&As[cur][row * 128 + ((kk * 64 + g4 * 16) ^ ((row & 7) << 4))]);
      }
      const int cc = kk * 8 + g4 * 2;     // fp32 16B-chunk index for k-cols [kk*32+g4*8, +8)
#pragma unroll
      for (int n = 0; n < 4; ++n) {
        int row = wc + n * 16 + r16;
        const unsigned char* wrp = &Wf[cur][row * 256];
        floatx4 w0 = *(const floatx4*)(wrp + ((cc ^ (row & 15)) << 4));
        floatx4 w1 = *(const floatx4*)(wrp + (((cc + 1) ^ (row & 15)) << 4));
        union { unsigned u[4]; short8 v; } pk;
        pk.u[0] = pack2bf(w0[0], w0[1]);
        pk.u[1] = pack2bf(w0[2], w0[3]);
        pk.u[2] = pack2bf(w1[0], w1[1]);
        pk.u[3] = pack2bf(w1[2], w1[3]);
        bf[n] = pk.v;
      }
#pragma unroll
      for (int m = 0; m < 2; ++m)
#pragma unroll
        for (int n = 0; n < 4; ++n)
          acc[m][n] = __builtin_amdgcn_mfma_f32_16x16x32_bf16(af[m], bf[n], acc[m][n], 0, 0, 0);
    }
    __syncthreads();
    cur ^= 1;
  }

#pragma unroll
  for (int m = 0; m < 2; ++m)
#pragma unroll
    for (int n = 0; n < 4; ++n)
#pragma unroll
      for (int j = 0; j < 4; ++j)
        C[(size_t)(m0 + wr + m * 16 + g4 * 4 + j) * ldc + (n0 + wc + n * 16 + r16)] = acc[m][n][j];
}

// ---------------------------------------------------------------- bf16 GEMM via global_load_lds (verified)
__global__ __launch_bounds__(256, 3)
void gemm_bf_kernel(const unsigned short* __restrict__ A,
                    const unsigned short* __restrict__ W,
                    float* __restrict__ C,
                    int M, int N, int K, int ldc, int GM)
{
  __shared__ __align__(16) unsigned char As[2][64 * 128];
  __shared__ __align__(16) unsigned char Bs[2][128 * 128];

  const int nwg = gridDim.x;
  int orig = blockIdx.x;
  int wg = (orig & 7) * (nwg >> 3) + (orig >> 3);
  const int mt = wg % GM, nt = wg / GM;
  const int m0 = mt * 64, n0 = nt * 128;

  const int tid = threadIdx.x;
  const int wid = tid >> 6, lane = tid & 63;
  const int g4 = lane >> 4, r16 = lane & 15;
  const int wr = (wid >> 1) * 32, wc = (wid & 1) * 64;

  const int lr = lane >> 3, lc = lane & 7;
  const unsigned short* Arow[2];
  const unsigned short* Wrow[4];
#pragma unroll
  for (int i = 0; i < 2; ++i) {
    int r = (wid * 2 + i) * 8 + lr;
    Arow[i] = A + (size_t)(m0 + r) * K + (lc ^ (r & 7)) * 8;
  }
#pragma unroll
  for (int i = 0; i < 4; ++i) {
    int r = (wid * 4 + i) * 8 + lr;
    Wrow[i] = W + (size_t)(n0 + r) * K + (lc ^ (r & 7)) * 8;
  }

  auto stage = [&](int buf, int kt) {
    const int kb = kt * 64;
#pragma unroll
    for (int i = 0; i < 2; ++i)
      gload_lds16(Arow[i] + kb, &As[buf][(wid * 2 + i) * 1024]);
#pragma unroll
    for (int i = 0; i < 4; ++i)
      gload_lds16(Wrow[i] + kb, &Bs[buf][(wid * 4 + i) * 1024]);
  };

  floatx4 acc[2][4];
#pragma unroll
  for (int m = 0; m < 2; ++m)
#pragma unroll
    for (int n = 0; n < 4; ++n) acc[m][n] = (floatx4){0.f, 0.f, 0.f, 0.f};

  const int NK = K >> 6;
  stage(0, 0);
  __syncthreads();
  int cur = 0;
  for (int kt = 0; kt < NK; ++kt) {
    if (kt + 1 < NK) stage(cur ^ 1, kt + 1);
#pragma unroll
    for (int kk = 0; kk < 2; ++kk) {
      const int kb = kk * 64 + g4 * 16;
      short8 af[2], bf[4];
#pragma unroll
      for (int m = 0; m < 2; ++m) {
        int row = wr + m * 16 + r16;
        af[m] = *(const short8*)(&As[cur][row * 128 + (kb ^ ((row & 7) << 4))]);
      }
#pragma unroll
      for (int n = 0; n < 4; ++n) {
        int row = wc + n * 16 + r16;
        bf[n] = *(const short8*)(&Bs[cur][row * 128 + (kb ^ ((row & 7) << 4))]);
      }
#pragma unroll
      for (int m = 0; m < 2; ++m)
#pragma unroll
        for (int n = 0; n < 4; ++n)
          acc[m][n] = __builtin_amdgcn_mfma_f32_16x16x32_bf16(af[m], bf[n], acc[m][n], 0, 0, 0);
    }
    __syncthreads();
    cur ^= 1;
  }

#pragma unroll
  for (int m = 0; m < 2; ++m)
#pragma unroll
    for (int n = 0; n < 4; ++n)
#pragma unroll
      for (int j = 0; j < 4; ++j)
        C[(size_t)(m0 + wr + m * 16 + g4 * 4 + j) * ldc + (n0 + wc + n * 16 + r16)] = acc[m][n][j];
}

// ---------------------------------------------------------------- fallback GEMM (fp32 weights, inline cvt)
__global__ __launch_bounds__(256, 2)
void gemm_kernel(const unsigned short* __restrict__ A,
                 const float* __restrict__ W0, const float* __restrict__ W1, const float* __restrict__ W2,
                 int n1, int n2,
                 float* __restrict__ C,
                 int M, int N, int K, int GM)
{
  __shared__ __align__(16) unsigned char As[2][128 * 128];
  __shared__ __align__(16) unsigned char Bs[2][128 * 128];

  const int nwg = gridDim.x;
  int orig = blockIdx.x;
  int xcd = orig & 7, loc = orig >> 3;
  int q = nwg >> 3, r = nwg & 7;
  int wg = (xcd < r ? xcd * (q + 1) : r * (q + 1) + (xcd - r) * q) + loc;
  const int mt = wg % GM, nt = wg / GM;
  const int m0 = mt * 128, n0 = nt * 128;

  const int tid = threadIdx.x;
  const int wid = tid >> 6, lane = tid & 63;
  const int g4 = lane >> 4, r16 = lane & 15;
  const int wr = (wid >> 1) * 64, wc = (wid & 1) * 64;

  int srow[4], skc[4];
  const float* wptr[4];
#pragma unroll
  for (int i = 0; i < 4; ++i) {
    int c = tid + 256 * i;
    srow[i] = c >> 3; skc[i] = c & 7;
    int ng = n0 + srow[i];
    wptr[i] = (ng < n1) ? (W0 + (size_t)ng * K)
            : (ng < n2) ? (W1 + (size_t)(ng - n1) * K)
                        : (W2 + (size_t)(ng - n2) * K);
  }

  short8 ar[4]; floatx4 br[8];
  auto load_tile = [&](int kt) {
    int kb = kt * 64;
#pragma unroll
    for (int i = 0; i < 4; ++i) {
      ar[i] = *(const short8*)(A + (size_t)(m0 + srow[i]) * K + kb + skc[i] * 8);
      br[2 * i]     = *(const floatx4*)(wptr[i] + kb + skc[i] * 8);
      br[2 * i + 1] = *(const floatx4*)(wptr[i] + kb + skc[i] * 8 + 4);
    }
  };
  auto write_tile = [&](int buf) {
#pragma unroll
    for (int i = 0; i < 4; ++i) {
      int off = srow[i] * 128 + ((skc[i] * 16) ^ ((srow[i] & 7) << 4));
      *(short8*)(&As[buf][off]) = ar[i];
      short8 bb;
      bb[0] = (short)f2bf(br[2 * i][0]);     bb[1] = (short)f2bf(br[2 * i][1]);
      bb[2] = (short)f2bf(br[2 * i][2]);     bb[3] = (short)f2bf(br[2 * i][3]);
      bb[4] = (short)f2bf(br[2 * i + 1][0]); bb[5] = (short)f2bf(br[2 * i + 1][1]);
      bb[6] = (short)f2bf(br[2 * i + 1][2]); bb[7] = (short)f2bf(br[2 * i + 1][3]);
      *(short8*)(&Bs[buf][off]) = bb;
    }
  };

  floatx4 acc[4][4];
#pragma unroll
  for (int m = 0; m < 4; ++m)
#pragma unroll
    for (int n = 0; n < 4; ++n) acc[m][n] = (floatx4){0.f, 0.f, 0.f, 0.f};

  const int NK = K >> 6;
  load_tile(0);
  write_tile(0);
  __syncthreads();
  int cur = 0;
  for (int kt = 0; kt < NK; ++kt) {
    if (kt + 1 < NK) load_tile(kt + 1);
#pragma unroll
    for (int kk = 0; kk < 2; ++kk) {
      const int kb = kk * 32 + g4 * 8;
      short8 af[4], bfr[4];
#pragma unroll
      for (int m = 0; m < 4; ++m) {
        int row = wr + m * 16 + r16;
        af[m] = *(const short8*)(&As[cur][row * 128 + ((kb * 2) ^ ((row & 7) << 4))]);
      }
#pragma unroll
      for (int n = 0; n < 4; ++n) {
        int row = wc + n * 16 + r16;
        bfr[n] = *(const short8*)(&Bs[cur][row * 128 + ((kb * 2) ^ ((row & 7) << 4))]);
      }
#pragma unroll
      for (int m = 0; m < 4; ++m)
#pragma unroll
        for (int n = 0; n < 4; ++n)
          acc[m][n] = __builtin_amdgcn_mfma_f32_16x16x32_bf16(af[m], bfr[n], acc[m][n], 0, 0, 0);
    }
    if (kt + 1 < NK) write_tile(cur ^ 1);
    __syncthreads();
    cur ^= 1;
  }

#pragma unroll
  for (int m = 0; m < 4; ++m)
#pragma unroll
    for (int n = 0; n < 4; ++n)
#pragma unroll
      for (int j = 0; j < 4; ++j)
        C[(size_t)(m0 + wr + m * 16 + g4 * 4 + j) * N + (n0 + wc + n * 16 + r16)] = acc[m][n][j];
}

// ---------------------------------------------------------------- RoPE on q -> bf16 (s, nh*hd), pre-scaled by 1/sqrt(hd)
__global__ void rope_q_kernel(const float* __restrict__ qkv, const float* __restrict__ fc,
                              const float* __restrict__ fs, unsigned short* __restrict__ qb)
{
  const int s = blockIdx.x, t = threadIdx.x;
  const int head = t >> 3, e0 = (t & 7) * 8;
  const float* base = qkv + (size_t)s * NQKV + head * HD + e0;
  floatx4 xr0 = *(const floatx4*)(base);
  floatx4 xr1 = *(const floatx4*)(base + 4);
  floatx4 xi0 = *(const floatx4*)(base + 64);
  floatx4 xi1 = *(const floatx4*)(base + 68);
  floatx4 c0 = *(const floatx4*)(fc + s * 64 + e0);
  floatx4 c1 = *(const floatx4*)(fc + s * 64 + e0 + 4);
  floatx4 s0 = *(const floatx4*)(fs + s * 64 + e0);
  floatx4 s1 = *(const floatx4*)(fs + s * 64 + e0 + 4);
  short8 outr, outi;
#pragma unroll
  for (int j = 0; j < 4; ++j) {
    outr[j]     = (short)f2bf((xr0[j] * c0[j] - xi0[j] * s0[j]) * QSCALE);
    outr[4 + j] = (short)f2bf((xr1[j] * c1[j] - xi1[j] * s1[j]) * QSCALE);
    outi[j]     = (short)f2bf((xr0[j] * s0[j] + xi0[j] * c0[j]) * QSCALE);
    outi[4 + j] = (short)f2bf((xr1[j] * s1[j] + xi1[j] * c1[j]) * QSCALE);
  }
  unsigned short* ob = qb + (size_t)s * D_MODEL + head * HD + e0;
  *(short8*)ob = outr;
  *(short8*)(ob + 64) = outi;
}

// ---------------------------------------------------------------- fused K prep: blocks 0-127 rope_k, 128-383 cache_k
__global__ void prep_k_kernel(const float* __restrict__ qkv, const float* __restrict__ fc,
                              const float* __restrict__ fs, const float* __restrict__ kc,
                              float* __restrict__ kh, unsigned short* __restrict__ khb)
{
  __shared__ __align__(16) unsigned char smem[128 * 65 * 4];
  const int tid = threadIdx.x;

  if (blockIdx.x < 128) {
    float (*T)[65] = (float(*)[65])smem;
    const int b = blockIdx.x;
    const int n = b >> 4, s0 = (b & 15) * 64;
    const int sl = tid >> 2, e0 = (tid & 3) * 16;
    const int s = s0 + sl;
    const float* base = qkv + (size_t)s * NQKV + D_MODEL + n * HD;
    float xr[16], xi[16], cc[16], sn[16];
#pragma unroll
    for (int i = 0; i < 16; i += 4) {
      *(floatx4*)(xr + i) = *(const floatx4*)(base + e0 + i);
      *(floatx4*)(xi + i) = *(const floatx4*)(base + 64 + e0 + i);
      *(floatx4*)(cc + i) = *(const floatx4*)(fc + s * 64 + e0 + i);
      *(floatx4*)(sn + i) = *(const floatx4*)(fs + s * 64 + e0 + i);
    }
    short8 r0, r1, i0, i1;
#pragma unroll
    for (int i = 0; i < 16; ++i) {
      float vr = xr[i] * cc[i] - xi[i] * sn[i];
      float vi = xr[i] * sn[i] + xi[i] * cc[i];
      T[e0 + i][sl] = vr;
      T[64 + e0 + i][sl] = vi;
      unsigned short br = f2bf(vr), bi = f2bf(vi);
      if (i < 8) { r0[i] = (short)br; i0[i] = (short)bi; }
      else       { r1[i - 8] = (short)br; i1[i - 8] = (short)bi; }
    }
    unsigned short* kb = khb + ((size_t)n * T_TOT + CACHE_T + s) * HD;
    *(short8*)(kb + e0) = r0;       *(short8*)(kb + e0 + 8) = r1;
    *(short8*)(kb + 64 + e0) = i0;  *(short8*)(kb + 64 + e0 + 8) = i1;
    __syncthreads();
    const int e = tid >> 1, hf = tid & 1;
    float* dst = kh + ((size_t)n * HD + e) * T_TOT + CACHE_T + s0 + hf * 32;
#pragma unroll
    for (int i = 0; i < 32; i += 4) {
      floatx4 v;
      v[0] = T[e][hf * 32 + i]; v[1] = T[e][hf * 32 + i + 1];
      v[2] = T[e][hf * 32 + i + 2]; v[3] = T[e][hf * 32 + i + 3];
      *(floatx4*)(dst + i) = v;
    }
  } else {
    unsigned short (*T)[72] = (unsigned short(*)[72])smem;
    const int b = blockIdx.x - 128;
    const int n = b >> 5, et = (b >> 4) & 1, tt = b & 15;
    const int e0 = et * 64, t0 = tt * 64;
    const int el = tid >> 2, tc = (tid & 3) * 16;
    const float* src = kc + ((size_t)n * HD + e0 + el) * CACHE_T + t0 + tc;
    float* dst = kh + ((size_t)n * HD + e0 + el) * T_TOT + t0 + tc;
#pragma unroll
    for (int i = 0; i < 16; i += 4) {
      floatx4 v = *(const floatx4*)(src + i);
      *(floatx4*)(dst + i) = v;
      T[tc + i][el] = f2bf(v[0]); T[tc + i + 1][el] = f2bf(v[1]);
      T[tc + i + 2][el] = f2bf(v[2]); T[tc + i + 3][el] = f2bf(v[3]);
    }
    __syncthreads();
    const int tl = tid >> 2, ec = (tid & 3) * 16;
    unsigned short* ob = khb + ((size_t)n * T_TOT + t0 + tl) * HD + e0 + ec;
#pragma unroll
    for (int i = 0; i < 16; i += 8) *(short8*)(ob + i) = *(const short8*)(&T[tl][ec + i]);
  }
}

// ---------------------------------------------------------------- fused V prep: blocks 0-127 v_scatter, 128-255 cache_v
__global__ void prep_v_kernel(const float* __restrict__ qkv, const float* __restrict__ vc,
                              float* __restrict__ vh, unsigned short* __restrict__ vtb)
{
  __shared__ __align__(16) unsigned short T[128][72];
  const int tid = threadIdx.x;

  if (blockIdx.x < 128) {
    const int b = blockIdx.x;
    const int n = b >> 4, s0 = (b & 15) * 64;
    const int sl = tid >> 2, e0 = (tid & 3) * 32;
    const float* src = qkv + (size_t)(s0 + sl) * NQKV + D_MODEL + NKV * HD + n * HD + e0;
    float* dst = vh + ((size_t)n * T_TOT + CACHE_T + s0 + sl) * HD + e0;
#pragma unroll
    for (int i = 0; i < 32; i += 4) {
      floatx4 v = *(const floatx4*)(src + i);
      *(floatx4*)(dst + i) = v;
      T[e0 + i][sl] = f2bf(v[0]); T[e0 + i + 1][sl] = f2bf(v[1]);
      T[e0 + i + 2][sl] = f2bf(v[2]); T[e0 + i + 3][sl] = f2bf(v[3]);
    }
    __syncthreads();
    const int e = tid >> 1, hf = tid & 1;
    unsigned short* ob = vtb + ((size_t)n * HD + e) * T_TOT + CACHE_T + s0 + hf * 32;
#pragma unroll
    for (int i = 0; i < 32; i += 8) *(short8*)(ob + i) = *(const short8*)(&T[e][hf * 32 + i]);
  } else {
    const int b = blockIdx.x - 128;
    const int n = b >> 4, t0 = (b & 15) * 64;
    const int tl = tid >> 2, e0 = (tid & 3) * 32;
    const float* src = vc + ((size_t)n * CACHE_T + t0 + tl) * HD + e0;
    float* dst = vh + ((size_t)n * T_TOT + t0 + tl) * HD + e0;
#pragma unroll
    for (int i = 0; i < 32; i += 4) {
      floatx4 v = *(const floatx4*)(src + i);
      *(floatx4*)(dst + i) = v;
      T[e0 + i][tl] = f2bf(v[0]); T[e0 + i + 1][tl] = f2bf(v[1]);
      T[e0 + i + 2][tl] = f2bf(v[2]); T[e0 + i + 3][tl] = f2bf(v[3]);
    }
    __syncthreads();
    const int e = tid >> 1, hf = tid & 1;
    unsigned short* ob = vtb + ((size_t)n * HD + e) * T_TOT + t0 + hf * 32;
#pragma unroll
    for (int i = 0; i < 32; i += 8) *(short8*)(ob + i) = *(const short8*)(&T[e][hf * 32 + i]);
  }
}

// ---------------------------------------------------------------- flash attention: swapped-QK 32x32 MFMA, in-register softmax
__global__ __launch_bounds__(256, 2)
void attn_kernel(const unsigned short* __restrict__ Qb, const unsigned short* __restrict__ Kb,
                 const unsigned short* __restrict__ Vb, const float* __restrict__ mask,
                 const int* __restrict__ flag, unsigned short* __restrict__ Ob,
                 float* __restrict__ Upart, float* __restrict__ mlpart, int nsplit)
{
  __shared__ __align__(16) unsigned char KL[2][64 * 256];
  __shared__ __align__(16) unsigned char VL[2][128 * 128];

  const int nwg = gridDim.x;
  int orig = blockIdx.x;
  int wg = (orig & 7) * (nwg >> 3) + (orig >> 3);
  const int per_n = 32 * nsplit;
  const int nkv = wg / per_n;
  const int rem = wg % per_n;
  const int kvs = rem >> 5;
  const int inner = rem & 31;
  const int h = nkv * 4 + (inner >> 3);
  const int qt = inner & 7;
  const int TKV = T_TOT / nsplit;

  const int tid = threadIdx.x, wid = tid >> 6, lane = tid & 63;
  const int l31 = lane & 31, hi = lane >> 5;
  const int qrow = qt * 128 + wid * 32 + l31;
  const bool use_mask = (*flag) != 0;

  short8 qf[8];
#pragma unroll
  for (int c = 0; c < 8; ++c)
    qf[c] = *(const short8*)(Qb + (size_t)qrow * D_MODEL + h * HD + c * 16 + hi * 8);

  floatx16 acc[4];
#pragma unroll
  for (int et = 0; et < 4; ++et)
    acc[et] = (floatx16){0.f,0.f,0.f,0.f,0.f,0.f,0.f,0.f,0.f,0.f,0.f,0.f,0.f,0.f,0.f,0.f};
  float m = -1e30f, l = 0.f;

  const unsigned short* Kbase = Kb + (size_t)nkv * T_TOT * HD + (size_t)kvs * TKV * HD;
  const unsigned short* Vbase = Vb + (size_t)nkv * HD * T_TOT + (size_t)kvs * TKV;

  const unsigned short* kp[4];
  const unsigned short* vp[4];
  int kbase_off[4], vbase_off[4];
#pragma unroll
  for (int i = 0; i < 4; ++i) {
    int krow = wid * 16 + i * 4 + (lane >> 4);
    int kch  = (lane & 15) ^ (krow & 7);
    kp[i] = Kbase + (size_t)krow * HD + kch * 8;
    kbase_off[i] = (wid * 16 + i * 4) * 256;
    int vrow = wid * 32 + i * 8 + (lane >> 3);
    int vch  = (lane & 7) ^ (vrow & 7);
    vp[i] = Vbase + (size_t)vrow * T_TOT + vch * 8;
    vbase_off[i] = (wid * 32 + i * 8) * 128;
  }

#pragma unroll
  for (int i = 0; i < 4; ++i) gload_lds16(kp[i], &KL[0][kbase_off[i]]);
#pragma unroll
  for (int i = 0; i < 4; ++i) gload_lds16(vp[i], &VL[0][vbase_off[i]]);
#pragma unroll
  for (int i = 0; i < 4; ++i) { kp[i] += 64 * HD; vp[i] += 64; }
  __syncthreads();

  int cur = 0;
  for (int t0 = 0; t0 < TKV; t0 += 64) {
    if (t0 + 64 < TKV) {
#pragma unroll
      for (int i = 0; i < 4; ++i) gload_lds16(kp[i], &KL[cur ^ 1][kbase_off[i]]);
#pragma unroll
      for (int i = 0; i < 4; ++i) gload_lds16(vp[i], &VL[cur ^ 1][vbase_off[i]]);
#pragma unroll
      for (int i = 0; i < 4; ++i) { kp[i] += 64 * HD; vp[i] += 64; }
    }

    floatx16 sc[2];
#pragma unroll
    for (int ts = 0; ts < 2; ++ts) {
      sc[ts] = (floatx16){0.f,0.f,0.f,0.f,0.f,0.f,0.f,0.f,0.f,0.f,0.f,0.f,0.f,0.f,0.f,0.f};
      const int krow = ts * 32 + l31;
      const int swz = (krow & 7) << 4;
      const unsigned char* kr = &KL[cur][krow * 256];
#pragma unroll
      for (int c = 0; c < 8; ++c) {
        short8 kf = *(const short8*)(kr + ((c * 32 + hi * 16) ^ swz));
        sc[ts] = __builtin_amdgcn_mfma_f32_32x32x16_bf16(kf, qf[c], sc[ts], 0, 0, 0);
      }
    }

    if (use_mask) {
#pragma unroll
      for (int ts = 0; ts < 2; ++ts)
#pragma unroll
        for (int r = 0; r < 16; ++r) {
          int tg = kvs * TKV + t0 + ts * 32 + (r & 3) + 8 * (r >> 2) + 4 * hi;
          sc[ts][r] += mask[(size_t)qrow * T_TOT + tg];
        }
    }

    float pm = sc[0][0];
#pragma unroll
    for (int r = 1; r < 16; ++r) pm = fmaxf(pm, sc[0][r]);
#pragma unroll
    for (int r = 0; r < 16; ++r) pm = fmaxf(pm, sc[1][r]);
    pm = fmaxf(pm, __shfl_xor(pm, 32));

    if (__any(pm > m + 8.f)) {
      float nm = fmaxf(m, pm);
      float corr = __expf(m - nm);
      m = nm; l *= corr;
#pragma unroll
      for (int r = 0; r < 16; ++r) {
        float cr = __shfl(corr, (r & 3) + 8 * (r >> 2) + 4 * hi);
#pragma unroll
        for (int et = 0; et < 4; ++et) acc[et][r] *= cr;
      }
    }

    unsigned cpk[4][4];
    float ls = 0.f;
#pragma unroll
    for (int ts = 0; ts < 2; ++ts)
#pragma unroll
      for (int i = 0; i < 8; ++i) {
        float plo = __expf(sc[ts][2 * i] - m);
        float phi = __expf(sc[ts][2 * i + 1] - m);
        ls += plo + phi;
        cpk[ts * 2 + (i >> 2)][i & 3] = pack2bf(plo, phi);
      }
    ls += __shfl_xor(ls, 32);
    l += ls;

    short8 pa[4];
#pragma unroll
    for (int tc = 0; tc < 4; ++tc) {
      unsigned s0 = (unsigned)__shfl_xor((int)cpk[tc][0], 32);
      unsigned s1 = (unsigned)__shfl_xor((int)cpk[tc][1], 32);
      unsigned s2 = (unsigned)__shfl_xor((int)cpk[tc][2], 32);
      unsigned s3 = (unsigned)__shfl_xor((int)cpk[tc][3], 32);
      union { unsigned u[4]; short8 v; } fr;
      fr.u[0] = hi ? s2 : cpk[tc][0];
      fr.u[1] = hi ? s3 : cpk[tc][1];
      fr.u[2] = hi ? cpk[tc][2] : s0;
      fr.u[3] = hi ? cpk[tc][3] : s1;
      pa[tc] = fr.v;
    }

#pragma unroll
    for (int et = 0; et < 4; ++et) {
      const int vrow = et * 32 + l31;
      const int swz = (vrow & 7) << 4;
      const unsigned char* vr = &VL[cur][vrow * 128];
#pragma unroll
      for (int tc = 0; tc < 4; ++tc) {
        short8 vf = *(const short8*)(vr + ((tc * 32 + hi * 16) ^ swz));
        acc[et] = __builtin_amdgcn_mfma_f32_32x32x16_bf16(pa[tc], vf, acc[et], 0, 0, 0);
      }
    }
    __syncthreads();
    cur ^= 1;
  }

  if (nsplit == 2) {
    float* Ub = Upart + (size_t)kvs * (NHEAD * S_LEN) * HD;
#pragma unroll
    for (int et = 0; et < 4; ++et)
#pragma unroll
      for (int r = 0; r < 16; ++r) {
        int q = qt * 128 + wid * 32 + (r & 3) + 8 * (r >> 2) + 4 * hi;
        Ub[((size_t)h * S_LEN + q) * HD + et * 32 + l31] = acc[et][r];
      }
    if (lane < 32) {
      float* mlp = mlpart + ((size_t)kvs * (NHEAD * S_LEN) + (size_t)h * S_LEN + qrow) * 2;
      mlp[0] = m; mlp[1] = l;
    }
  } else {
    float inv = 1.0f / l;
#pragma unroll
    for (int et = 0; et < 4; ++et)
#pragma unroll
      for (int r = 0; r < 16; ++r) {
        float ir = __shfl(inv, (r & 3) + 8 * (r >> 2) + 4 * hi);
        int q = qt * 128 + wid * 32 + (r & 3) + 8 * (r >> 2) + 4 * hi;
        Ob[(size_t)q * D_MODEL + h * HD + et * 32 + l31] = f2bf(acc[et][r] * ir);
      }
  }
}

// ---------------------------------------------------------------- exact online-softmax merge of 2 KV halves
__global__ void attn_combine_kernel(const float* __restrict__ U, const float* __restrict__ ml,
                                    unsigned short* __restrict__ Ob)
{
  const int t = blockIdx.x * 256 + threadIdx.x;
  const int r = t >> 4;
  const int e0 = (t & 15) * 8;
  const float m1 = ml[(size_t)r * 2],                     l1 = ml[(size_t)r * 2 + 1];
  const float m2 = ml[((size_t)(NHEAD * S_LEN) + r) * 2], l2 = ml[((size_t)(NHEAD * S_LEN) + r) * 2 + 1];
  const float M = fmaxf(m1, m2);
  const float a1 = __expf(m1 - M), a2 = __expf(m2 - M);
  const float inv = 1.0f / (l1 * a1 + l2 * a2);
  const float* u1 = U + (size_t)r * HD + e0;
  const float* u2 = U + (size_t)(NHEAD * S_LEN) * HD + (size_t)r * HD + e0;
  floatx4 x1a = *(const floatx4*)u1, x1b = *(const floatx4*)(u1 + 4);
  floatx4 x2a = *(const floatx4*)u2, x2b = *(const floatx4*)(u2 + 4);
  const int s = r & (S_LEN - 1), hh = r >> 10;
  unsigned short* ob = Ob + (size_t)s * D_MODEL + hh * HD + e0;
  short8 o;
#pragma unroll
  for (int k = 0; k < 4; ++k) {
    o[k]     = (short)f2bf((x1a[k] * a1 + x2a[k] * a2) * inv);
    o[4 + k] = (short)f2bf((x1b[k] * a1 + x2b[k] * a2) * inv);
  }
  *(short8*)ob = o;
}

// ----------------------------------------------------------------
extern "C" void kernel_launch(void* const* d_in, const int* in_sizes, int n_in,
                              void* d_out, int out_size, void* d_ws, size_t ws_size,
                              hipStream_t stream)
{
  const float* hs   = (const float*)d_in[0];
  const float* fc   = (const float*)d_in[1];
  const float* fs   = (const float*)d_in[2];
  const float* mask = (const float*)d_in[3];
  const float* kc   = (const float*)d_in[4];
  const float* vc   = (const float*)d_in[5];
  const float* wq   = (const float*)d_in[6];
  const float* wk   = (const float*)d_in[7];
  const float* wv   = (const float*)d_in[8];
  const float* wo   = (const float*)d_in[9];

  float* y  = (float*)d_out;                       // (1024, 4096)
  float* kh = y + (size_t)S_LEN * D_MODEL;         // (8, 128, 2048)
  float* vh = kh + (size_t)NKV * HD * T_TOT;       // (8, 2048, 128)

  char* ws = (char*)d_ws;
  unsigned short* hs_b   = (unsigned short*)ws;                     // 8,388,608 B (later reused as rope'd q)
  float* qkv             = (float*)(ws + 8388608u);                 // 25,165,824 B
  unsigned short* attn_o = (unsigned short*)(ws + 8388608u);        // alias (attn runs after qkv consumers)
  unsigned short* khb    = (unsigned short*)(ws + 33554432u);       // 4,194,304 B
  unsigned short* vtb    = (unsigned short*)(ws + 37748736u);       // 4,194,304 B
  int* flag              = (int*)(ws + 41943040u);
  unsigned short* slotW  = (unsigned short*)(ws + 41943296u);       // wo bf16 slot / attn partials

  const size_t base = 41943296ull;
  const bool mid = ws_size >= base + 33554432ull;        // wo bf16 slot fits
  const int nsplit = (ws_size >= base + 34078720ull) ? 2 : 1;
  float* Upart  = (float*)(ws + base);                   // 33,554,432 B (sequentially shared with slotW)
  float* mlpart = (float*)(ws + base + 33554432u);       //    524,288 B

  hipMemsetAsync(flag, 0, 4, stream);
  mask_flag_kernel<<<256, 256, 0, stream>>>(mask, S_LEN * T_TOT, flag);
  convf2b_kernel<<<2048, 256, 0, stream>>>(hs, hs_b, S_LEN * D_MODEL / 8);

  // QKV projection: fused fp32-weight GEMM (DMA-to-LDS + fragment-time cvt) — no weight pre-conversion
  gemm_fw2_kernel<<<768, 256, 0, stream>>>(hs_b, wq, wk, wv, 4096, 5120, qkv,
                                           1024, 6144, 4096, 6144, 16);

  rope_q_kernel<<<1024, 256, 0, stream>>>(qkv, fc, fs, hs_b);
  prep_k_kernel<<<384, 256, 0, stream>>>(qkv, fc, fs, kc, kh, khb);
  prep_v_kernel<<<256, 256, 0, stream>>>(qkv, vc, vh, vtb);

  attn_kernel<<<256 * nsplit, 256, 0, stream>>>(hs_b, khb, vtb, mask, flag, attn_o,
                                                Upart, mlpart, nsplit);
  if (nsplit == 2)
    attn_combine_kernel<<<2048, 256, 0, stream>>>(Upart, mlpart, attn_o);

  // Output projection: verified conv + bf16 GEMM (hedge: unchanged path)
  if (mid) {
    convf2b_kernel<<<2048, 256, 0, stream>>>(wo, slotW, D_MODEL * D_MODEL / 8);
    gemm_bf_kernel<<<512, 256, 0, stream>>>(attn_o, slotW, y, 1024, 4096, 4096, 4096, 16);
  } else {
    gemm_kernel<<<256, 256, 0, stream>>>(attn_o, wo, wo, wo, 1 << 29, 1 << 29, y, 1024, 4096, 4096, 8);
  }
}

// Round 12
// 241.593 us; speedup vs baseline: 1.4982x; 1.4982x over previous
//
#include <hip/hip_runtime.h>
#include <hip/hip_bf16.h>
#include <stdint.h>

#define S_LEN 1024
#define D_MODEL 4096
#define NHEAD 32
#define NKV 8
#define HD 128
#define CACHE_T 1024
#define T_TOT 2048
#define NQKV 6144
#define QSCALE 0.08838834764831845f

typedef __attribute__((ext_vector_type(8))) short short8;
typedef __attribute__((ext_vector_type(4))) float floatx4;
typedef __attribute__((ext_vector_type(16))) float floatx16;

__device__ __forceinline__ unsigned short f2bf(float f) {
  union { float f; uint32_t u; } v; v.f = f;
  uint32_t r = v.u + 0x7FFFu + ((v.u >> 16) & 1u);
  return (unsigned short)(r >> 16);
}

__device__ __forceinline__ unsigned pack2bf(float a, float b) {
  union { __hip_bfloat162 h2; unsigned u; } c;
  c.h2 = __float22bfloat162_rn(make_float2(a, b));
  return c.u;
}

__device__ __forceinline__ void gload_lds16(const void* g, void* s) {
  __builtin_amdgcn_global_load_lds((const __attribute__((address_space(1))) void*)g,
                                   (__attribute__((address_space(3))) void*)s, 16, 0, 0);
}

__device__ __forceinline__ void conv8(const float* __restrict__ in, unsigned short* __restrict__ out, int idx) {
  int i = idx * 8;
  floatx4 a = *(const floatx4*)(in + i);
  floatx4 b = *(const floatx4*)(in + i + 4);
  short8 o;
  o[0] = (short)f2bf(a[0]); o[1] = (short)f2bf(a[1]); o[2] = (short)f2bf(a[2]); o[3] = (short)f2bf(a[3]);
  o[4] = (short)f2bf(b[0]); o[5] = (short)f2bf(b[1]); o[6] = (short)f2bf(b[2]); o[7] = (short)f2bf(b[3]);
  *(short8*)(out + i) = o;
}

// ---------------------------------------------------------------- generic fp32 -> bf16 (n8 = count/8)
__global__ void convf2b_kernel(const float* __restrict__ in, unsigned short* __restrict__ out, int n8) {
  int stride = gridDim.x * blockDim.x;
  for (int t = blockIdx.x * blockDim.x + threadIdx.x; t < n8; t += stride)
    conv8(in, out, t);
}

// ---------------------------------------------------------------- mask nonzero flag (standalone, fallback path)
__global__ void mask_flag_kernel(const float* __restrict__ m, int n, int* __restrict__ flag) {
  int stride = gridDim.x * blockDim.x;
  bool nz = false;
  for (int i = blockIdx.x * blockDim.x + threadIdx.x; i < n; i += stride)
    nz |= (m[i] != 0.0f);
  if (nz) atomicOr(flag, 1);
}

// ---------------------------------------------------------------- FRONT: mask_flag + conv hs + conv wq/wk/wv (one launch)
// blocks [0,256) mask | [256,2304) hs | [2304,10496) wq | [10496,12544) wk | [12544,14592) wv
__global__ void front_kernel(const float* __restrict__ mask, int nmask, int* __restrict__ flag,
                             const float* __restrict__ hs, unsigned short* __restrict__ hs_b,
                             const float* __restrict__ wq, const float* __restrict__ wk,
                             const float* __restrict__ wv, unsigned short* __restrict__ slotW)
{
  const int b = blockIdx.x, tid = threadIdx.x;
  if (b < 256) {
    bool nz = false;
    for (int i = b * 256 + tid; i < nmask; i += 256 * 256)
      nz |= (mask[i] != 0.0f);
    if (nz) atomicOr(flag, 1);
  } else if (b < 2304) {
    conv8(hs, hs_b, (b - 256) * 256 + tid);
  } else if (b < 10496) {
    conv8(wq, slotW, (b - 2304) * 256 + tid);
  } else if (b < 12544) {
    conv8(wk, slotW + (size_t)4096 * 4096, (b - 10496) * 256 + tid);
  } else {
    conv8(wv, slotW + (size_t)5120 * 4096, (b - 12544) * 256 + tid);
  }
}

// ---------------------------------------------------------------- bf16 GEMM via global_load_lds (verified 65.5us @ qkv)
__global__ __launch_bounds__(256, 3)
void gemm_bf_kernel(const unsigned short* __restrict__ A,
                    const unsigned short* __restrict__ W,
                    float* __restrict__ C,
                    int M, int N, int K, int ldc, int GM)
{
  __shared__ __align__(16) unsigned char As[2][64 * 128];
  __shared__ __align__(16) unsigned char Bs[2][128 * 128];

  const int nwg = gridDim.x;
  int orig = blockIdx.x;
  int wg = (orig & 7) * (nwg >> 3) + (orig >> 3);
  const int mt = wg % GM, nt = wg / GM;
  const int m0 = mt * 64, n0 = nt * 128;

  const int tid = threadIdx.x;
  const int wid = tid >> 6, lane = tid & 63;
  const int g4 = lane >> 4, r16 = lane & 15;
  const int wr = (wid >> 1) * 32, wc = (wid & 1) * 64;

  const int lr = lane >> 3, lc = lane & 7;
  const unsigned short* Arow[2];
  const unsigned short* Wrow[4];
#pragma unroll
  for (int i = 0; i < 2; ++i) {
    int r = (wid * 2 + i) * 8 + lr;
    Arow[i] = A + (size_t)(m0 + r) * K + (lc ^ (r & 7)) * 8;
  }
#pragma unroll
  for (int i = 0; i < 4; ++i) {
    int r = (wid * 4 + i) * 8 + lr;
    Wrow[i] = W + (size_t)(n0 + r) * K + (lc ^ (r & 7)) * 8;
  }

  auto stage = [&](int buf, int kt) {
    const int kb = kt * 64;
#pragma unroll
    for (int i = 0; i < 2; ++i)
      gload_lds16(Arow[i] + kb, &As[buf][(wid * 2 + i) * 1024]);
#pragma unroll
    for (int i = 0; i < 4; ++i)
      gload_lds16(Wrow[i] + kb, &Bs[buf][(wid * 4 + i) * 1024]);
  };

  floatx4 acc[2][4];
#pragma unroll
  for (int m = 0; m < 2; ++m)
#pragma unroll
    for (int n = 0; n < 4; ++n) acc[m][n] = (floatx4){0.f, 0.f, 0.f, 0.f};

  const int NK = K >> 6;
  stage(0, 0);
  __syncthreads();
  int cur = 0;
  for (int kt = 0; kt < NK; ++kt) {
    if (kt + 1 < NK) stage(cur ^ 1, kt + 1);
#pragma unroll
    for (int kk = 0; kk < 2; ++kk) {
      const int kb = kk * 64 + g4 * 16;
      short8 af[2], bf[4];
#pragma unroll
      for (int m = 0; m < 2; ++m) {
        int row = wr + m * 16 + r16;
        af[m] = *(const short8*)(&As[cur][row * 128 + (kb ^ ((row & 7) << 4))]);
      }
#pragma unroll
      for (int n = 0; n < 4; ++n) {
        int row = wc + n * 16 + r16;
        bf[n] = *(const short8*)(&Bs[cur][row * 128 + (kb ^ ((row & 7) << 4))]);
      }
#pragma unroll
      for (int m = 0; m < 2; ++m)
#pragma unroll
        for (int n = 0; n < 4; ++n)
          acc[m][n] = __builtin_amdgcn_mfma_f32_16x16x32_bf16(af[m], bf[n], acc[m][n], 0, 0, 0);
    }
    __syncthreads();
    cur ^= 1;
  }

#pragma unroll
  for (int m = 0; m < 2; ++m)
#pragma unroll
    for (int n = 0; n < 4; ++n)
#pragma unroll
      for (int j = 0; j < 4; ++j)
        C[(size_t)(m0 + wr + m * 16 + g4 * 4 + j) * ldc + (n0 + wc + n * 16 + r16)] = acc[m][n][j];
}

// ---------------------------------------------------------------- fallback GEMM (fp32 weights, inline cvt)
__global__ __launch_bounds__(256, 2)
void gemm_kernel(const unsigned short* __restrict__ A,
                 const float* __restrict__ W0, const float* __restrict__ W1, const float* __restrict__ W2,
                 int n1, int n2,
                 float* __restrict__ C,
                 int M, int N, int K, int GM)
{
  __shared__ __align__(16) unsigned char As[2][128 * 128];
  __shared__ __align__(16) unsigned char Bs[2][128 * 128];

  const int nwg = gridDim.x;
  int orig = blockIdx.x;
  int xcd = orig & 7, loc = orig >> 3;
  int q = nwg >> 3, r = nwg & 7;
  int wg = (xcd < r ? xcd * (q + 1) : r * (q + 1) + (xcd - r) * q) + loc;
  const int mt = wg % GM, nt = wg / GM;
  const int m0 = mt * 128, n0 = nt * 128;

  const int tid = threadIdx.x;
  const int wid = tid >> 6, lane = tid & 63;
  const int g4 = lane >> 4, r16 = lane & 15;
  const int wr = (wid >> 1) * 64, wc = (wid & 1) * 64;

  int srow[4], skc[4];
  const float* wptr[4];
#pragma unroll
  for (int i = 0; i < 4; ++i) {
    int c = tid + 256 * i;
    srow[i] = c >> 3; skc[i] = c & 7;
    int ng = n0 + srow[i];
    wptr[i] = (ng < n1) ? (W0 + (size_t)ng * K)
            : (ng < n2) ? (W1 + (size_t)(ng - n1) * K)
                        : (W2 + (size_t)(ng - n2) * K);
  }

  short8 ar[4]; floatx4 br[8];
  auto load_tile = [&](int kt) {
    int kb = kt * 64;
#pragma unroll
    for (int i = 0; i < 4; ++i) {
      ar[i] = *(const short8*)(A + (size_t)(m0 + srow[i]) * K + kb + skc[i] * 8);
      br[2 * i]     = *(const floatx4*)(wptr[i] + kb + skc[i] * 8);
      br[2 * i + 1] = *(const floatx4*)(wptr[i] + kb + skc[i] * 8 + 4);
    }
  };
  auto write_tile = [&](int buf) {
#pragma unroll
    for (int i = 0; i < 4; ++i) {
      int off = srow[i] * 128 + ((skc[i] * 16) ^ ((srow[i] & 7) << 4));
      *(short8*)(&As[buf][off]) = ar[i];
      short8 bb;
      bb[0] = (short)f2bf(br[2 * i][0]);     bb[1] = (short)f2bf(br[2 * i][1]);
      bb[2] = (short)f2bf(br[2 * i][2]);     bb[3] = (short)f2bf(br[2 * i][3]);
      bb[4] = (short)f2bf(br[2 * i + 1][0]); bb[5] = (short)f2bf(br[2 * i + 1][1]);
      bb[6] = (short)f2bf(br[2 * i + 1][2]); bb[7] = (short)f2bf(br[2 * i + 1][3]);
      *(short8*)(&Bs[buf][off]) = bb;
    }
  };

  floatx4 acc[4][4];
#pragma unroll
  for (int m = 0; m < 4; ++m)
#pragma unroll
    for (int n = 0; n < 4; ++n) acc[m][n] = (floatx4){0.f, 0.f, 0.f, 0.f};

  const int NK = K >> 6;
  load_tile(0);
  write_tile(0);
  __syncthreads();
  int cur = 0;
  for (int kt = 0; kt < NK; ++kt) {
    if (kt + 1 < NK) load_tile(kt + 1);
#pragma unroll
    for (int kk = 0; kk < 2; ++kk) {
      const int kb = kk * 32 + g4 * 8;
      short8 af[4], bfr[4];
#pragma unroll
      for (int m = 0; m < 4; ++m) {
        int row = wr + m * 16 + r16;
        af[m] = *(const short8*)(&As[cur][row * 128 + ((kb * 2) ^ ((row & 7) << 4))]);
      }
#pragma unroll
      for (int n = 0; n < 4; ++n) {
        int row = wc + n * 16 + r16;
        bfr[n] = *(const short8*)(&Bs[cur][row * 128 + ((kb * 2) ^ ((row & 7) << 4))]);
      }
#pragma unroll
      for (int m = 0; m < 4; ++m)
#pragma unroll
        for (int n = 0; n < 4; ++n)
          acc[m][n] = __builtin_amdgcn_mfma_f32_16x16x32_bf16(af[m], bfr[n], acc[m][n], 0, 0, 0);
    }
    if (kt + 1 < NK) write_tile(cur ^ 1);
    __syncthreads();
    cur ^= 1;
  }

#pragma unroll
  for (int m = 0; m < 4; ++m)
#pragma unroll
    for (int n = 0; n < 4; ++n)
#pragma unroll
      for (int j = 0; j < 4; ++j)
        C[(size_t)(m0 + wr + m * 16 + g4 * 4 + j) * N + (n0 + wc + n * 16 + r16)] = acc[m][n][j];
}

// ---------------------------------------------------------------- PREP_ALL: rope_q [0,1024) + prep_k [1024,1408) + prep_v [1408,1664)
__global__ void prep_all_kernel(const float* __restrict__ qkv, const float* __restrict__ fc,
                                const float* __restrict__ fs, const float* __restrict__ kc,
                                const float* __restrict__ vc,
                                unsigned short* __restrict__ qb,
                                float* __restrict__ kh, unsigned short* __restrict__ khb,
                                float* __restrict__ vh, unsigned short* __restrict__ vtb)
{
  __shared__ __align__(16) unsigned char smem[128 * 65 * 4];
  const int blk = blockIdx.x, tid = threadIdx.x;

  if (blk < 1024) {
    // ---- rope_q body (s = blk), q pre-scaled by 1/sqrt(hd)
    const int s = blk;
    const int head = tid >> 3, e0 = (tid & 7) * 8;
    const float* base = qkv + (size_t)s * NQKV + head * HD + e0;
    floatx4 xr0 = *(const floatx4*)(base);
    floatx4 xr1 = *(const floatx4*)(base + 4);
    floatx4 xi0 = *(const floatx4*)(base + 64);
    floatx4 xi1 = *(const floatx4*)(base + 68);
    floatx4 c0 = *(const floatx4*)(fc + s * 64 + e0);
    floatx4 c1 = *(const floatx4*)(fc + s * 64 + e0 + 4);
    floatx4 s0 = *(const floatx4*)(fs + s * 64 + e0);
    floatx4 s1 = *(const floatx4*)(fs + s * 64 + e0 + 4);
    short8 outr, outi;
#pragma unroll
    for (int j = 0; j < 4; ++j) {
      outr[j]     = (short)f2bf((xr0[j] * c0[j] - xi0[j] * s0[j]) * QSCALE);
      outr[4 + j] = (short)f2bf((xr1[j] * c1[j] - xi1[j] * s1[j]) * QSCALE);
      outi[j]     = (short)f2bf((xr0[j] * s0[j] + xi0[j] * c0[j]) * QSCALE);
      outi[4 + j] = (short)f2bf((xr1[j] * s1[j] + xi1[j] * c1[j]) * QSCALE);
    }
    unsigned short* ob = qb + (size_t)s * D_MODEL + head * HD + e0;
    *(short8*)ob = outr;
    *(short8*)(ob + 64) = outi;
  } else if (blk < 1408) {
    const int bb = blk - 1024;
    if (bb < 128) {
      // ---- rope_k body
      float (*T)[65] = (float(*)[65])smem;
      const int n = bb >> 4, s0 = (bb & 15) * 64;
      const int sl = tid >> 2, e0 = (tid & 3) * 16;
      const int s = s0 + sl;
      const float* base = qkv + (size_t)s * NQKV + D_MODEL + n * HD;
      float xr[16], xi[16], cc[16], sn[16];
#pragma unroll
      for (int i = 0; i < 16; i += 4) {
        *(floatx4*)(xr + i) = *(const floatx4*)(base + e0 + i);
        *(floatx4*)(xi + i) = *(const floatx4*)(base + 64 + e0 + i);
        *(floatx4*)(cc + i) = *(const floatx4*)(fc + s * 64 + e0 + i);
        *(floatx4*)(sn + i) = *(const floatx4*)(fs + s * 64 + e0 + i);
      }
      short8 r0, r1, i0, i1;
#pragma unroll
      for (int i = 0; i < 16; ++i) {
        float vr = xr[i] * cc[i] - xi[i] * sn[i];
        float vi = xr[i] * sn[i] + xi[i] * cc[i];
        T[e0 + i][sl] = vr;
        T[64 + e0 + i][sl] = vi;
        unsigned short br = f2bf(vr), bi = f2bf(vi);
        if (i < 8) { r0[i] = (short)br; i0[i] = (short)bi; }
        else       { r1[i - 8] = (short)br; i1[i - 8] = (short)bi; }
      }
      unsigned short* kb = khb + ((size_t)n * T_TOT + CACHE_T + s) * HD;
      *(short8*)(kb + e0) = r0;       *(short8*)(kb + e0 + 8) = r1;
      *(short8*)(kb + 64 + e0) = i0;  *(short8*)(kb + 64 + e0 + 8) = i1;
      __syncthreads();
      const int e = tid >> 1, hf = tid & 1;
      float* dst = kh + ((size_t)n * HD + e) * T_TOT + CACHE_T + s0 + hf * 32;
#pragma unroll
      for (int i = 0; i < 32; i += 4) {
        floatx4 v;
        v[0] = T[e][hf * 32 + i]; v[1] = T[e][hf * 32 + i + 1];
        v[2] = T[e][hf * 32 + i + 2]; v[3] = T[e][hf * 32 + i + 3];
        *(floatx4*)(dst + i) = v;
      }
    } else {
      // ---- cache_k body
      unsigned short (*T)[72] = (unsigned short(*)[72])smem;
      const int b = bb - 128;
      const int n = b >> 5, et = (b >> 4) & 1, tt = b & 15;
      const int e0 = et * 64, t0 = tt * 64;
      const int el = tid >> 2, tc = (tid & 3) * 16;
      const float* src = kc + ((size_t)n * HD + e0 + el) * CACHE_T + t0 + tc;
      float* dst = kh + ((size_t)n * HD + e0 + el) * T_TOT + t0 + tc;
#pragma unroll
      for (int i = 0; i < 16; i += 4) {
        floatx4 v = *(const floatx4*)(src + i);
        *(floatx4*)(dst + i) = v;
        T[tc + i][el] = f2bf(v[0]); T[tc + i + 1][el] = f2bf(v[1]);
        T[tc + i + 2][el] = f2bf(v[2]); T[tc + i + 3][el] = f2bf(v[3]);
      }
      __syncthreads();
      const int tl = tid >> 2, ec = (tid & 3) * 16;
      unsigned short* ob = khb + ((size_t)n * T_TOT + t0 + tl) * HD + e0 + ec;
#pragma unroll
      for (int i = 0; i < 16; i += 8) *(short8*)(ob + i) = *(const short8*)(&T[tl][ec + i]);
    }
  } else {
    const int bb = blk - 1408;
    unsigned short (*T)[72] = (unsigned short(*)[72])smem;
    if (bb < 128) {
      // ---- v_scatter body
      const int n = bb >> 4, s0 = (bb & 15) * 64;
      const int sl = tid >> 2, e0 = (tid & 3) * 32;
      const float* src = qkv + (size_t)(s0 + sl) * NQKV + D_MODEL + NKV * HD + n * HD + e0;
      float* dst = vh + ((size_t)n * T_TOT + CACHE_T + s0 + sl) * HD + e0;
#pragma unroll
      for (int i = 0; i < 32; i += 4) {
        floatx4 v = *(const floatx4*)(src + i);
        *(floatx4*)(dst + i) = v;
        T[e0 + i][sl] = f2bf(v[0]); T[e0 + i + 1][sl] = f2bf(v[1]);
        T[e0 + i + 2][sl] = f2bf(v[2]); T[e0 + i + 3][sl] = f2bf(v[3]);
      }
      __syncthreads();
      const int e = tid >> 1, hf = tid & 1;
      unsigned short* ob = vtb + ((size_t)n * HD + e) * T_TOT + CACHE_T + s0 + hf * 32;
#pragma unroll
      for (int i = 0; i < 32; i += 8) *(short8*)(ob + i) = *(const short8*)(&T[e][hf * 32 + i]);
    } else {
      // ---- cache_v body
      const int b = bb - 128;
      const int n = b >> 4, t0 = (b & 15) * 64;
      const int tl = tid >> 2, e0 = (tid & 3) * 32;
      const float* src = vc + ((size_t)n * CACHE_T + t0 + tl) * HD + e0;
      float* dst = vh + ((size_t)n * T_TOT + t0 + tl) * HD + e0;
#pragma unroll
      for (int i = 0; i < 32; i += 4) {
        floatx4 v = *(const floatx4*)(src + i);
        *(floatx4*)(dst + i) = v;
        T[e0 + i][tl] = f2bf(v[0]); T[e0 + i + 1][tl] = f2bf(v[1]);
        T[e0 + i + 2][tl] = f2bf(v[2]); T[e0 + i + 3][tl] = f2bf(v[3]);
      }
      __syncthreads();
      const int e = tid >> 1, hf = tid & 1;
      unsigned short* ob = vtb + ((size_t)n * HD + e) * T_TOT + t0 + hf * 32;
#pragma unroll
      for (int i = 0; i < 32; i += 8) *(short8*)(ob + i) = *(const short8*)(&T[e][hf * 32 + i]);
    }
  }
}

// ---------------------------------------------------------------- flash attention: swapped-QK 32x32 MFMA, in-register softmax
__global__ __launch_bounds__(256, 2)
void attn_kernel(const unsigned short* __restrict__ Qb, const unsigned short* __restrict__ Kb,
                 const unsigned short* __restrict__ Vb, const float* __restrict__ mask,
                 const int* __restrict__ flag, unsigned short* __restrict__ Ob,
                 float* __restrict__ Upart, float* __restrict__ mlpart, int nsplit)
{
  __shared__ __align__(16) unsigned char KL[2][64 * 256];
  __shared__ __align__(16) unsigned char VL[2][128 * 128];

  const int nwg = gridDim.x;
  int orig = blockIdx.x;
  int wg = (orig & 7) * (nwg >> 3) + (orig >> 3);
  const int per_n = 32 * nsplit;
  const int nkv = wg / per_n;
  const int rem = wg % per_n;
  const int kvs = rem >> 5;
  const int inner = rem & 31;
  const int h = nkv * 4 + (inner >> 3);
  const int qt = inner & 7;
  const int TKV = T_TOT / nsplit;

  const int tid = threadIdx.x, wid = tid >> 6, lane = tid & 63;
  const int l31 = lane & 31, hi = lane >> 5;
  const int qrow = qt * 128 + wid * 32 + l31;
  const bool use_mask = (*flag) != 0;

  short8 qf[8];
#pragma unroll
  for (int c = 0; c < 8; ++c)
    qf[c] = *(const short8*)(Qb + (size_t)qrow * D_MODEL + h * HD + c * 16 + hi * 8);

  floatx16 acc[4];
#pragma unroll
  for (int et = 0; et < 4; ++et)
    acc[et] = (floatx16){0.f,0.f,0.f,0.f,0.f,0.f,0.f,0.f,0.f,0.f,0.f,0.f,0.f,0.f,0.f,0.f};
  float m = -1e30f, l = 0.f;

  const unsigned short* Kbase = Kb + (size_t)nkv * T_TOT * HD + (size_t)kvs * TKV * HD;
  const unsigned short* Vbase = Vb + (size_t)nkv * HD * T_TOT + (size_t)kvs * TKV;

  const unsigned short* kp[4];
  const unsigned short* vp[4];
  int kbase_off[4], vbase_off[4];
#pragma unroll
  for (int i = 0; i < 4; ++i) {
    int krow = wid * 16 + i * 4 + (lane >> 4);
    int kch  = (lane & 15) ^ (krow & 7);
    kp[i] = Kbase + (size_t)krow * HD + kch * 8;
    kbase_off[i] = (wid * 16 + i * 4) * 256;
    int vrow = wid * 32 + i * 8 + (lane >> 3);
    int vch  = (lane & 7) ^ (vrow & 7);
    vp[i] = Vbase + (size_t)vrow * T_TOT + vch * 8;
    vbase_off[i] = (wid * 32 + i * 8) * 128;
  }

#pragma unroll
  for (int i = 0; i < 4; ++i) gload_lds16(kp[i], &KL[0][kbase_off[i]]);
#pragma unroll
  for (int i = 0; i < 4; ++i) gload_lds16(vp[i], &VL[0][vbase_off[i]]);
#pragma unroll
  for (int i = 0; i < 4; ++i) { kp[i] += 64 * HD; vp[i] += 64; }
  __syncthreads();

  int cur = 0;
  for (int t0 = 0; t0 < TKV; t0 += 64) {
    if (t0 + 64 < TKV) {
#pragma unroll
      for (int i = 0; i < 4; ++i) gload_lds16(kp[i], &KL[cur ^ 1][kbase_off[i]]);
#pragma unroll
      for (int i = 0; i < 4; ++i) gload_lds16(vp[i], &VL[cur ^ 1][vbase_off[i]]);
#pragma unroll
      for (int i = 0; i < 4; ++i) { kp[i] += 64 * HD; vp[i] += 64; }
    }

    floatx16 sc[2];
#pragma unroll
    for (int ts = 0; ts < 2; ++ts) {
      sc[ts] = (floatx16){0.f,0.f,0.f,0.f,0.f,0.f,0.f,0.f,0.f,0.f,0.f,0.f,0.f,0.f,0.f,0.f};
      const int krow = ts * 32 + l31;
      const int swz = (krow & 7) << 4;
      const unsigned char* kr = &KL[cur][krow * 256];
#pragma unroll
      for (int c = 0; c < 8; ++c) {
        short8 kf = *(const short8*)(kr + ((c * 32 + hi * 16) ^ swz));
        sc[ts] = __builtin_amdgcn_mfma_f32_32x32x16_bf16(kf, qf[c], sc[ts], 0, 0, 0);
      }
    }

    if (use_mask) {
#pragma unroll
      for (int ts = 0; ts < 2; ++ts)
#pragma unroll
        for (int r = 0; r < 16; ++r) {
          int tg = kvs * TKV + t0 + ts * 32 + (r & 3) + 8 * (r >> 2) + 4 * hi;
          sc[ts][r] += mask[(size_t)qrow * T_TOT + tg];
        }
    }

    float pm = sc[0][0];
#pragma unroll
    for (int r = 1; r < 16; ++r) pm = fmaxf(pm, sc[0][r]);
#pragma unroll
    for (int r = 0; r < 16; ++r) pm = fmaxf(pm, sc[1][r]);
    pm = fmaxf(pm, __shfl_xor(pm, 32));

    if (__any(pm > m + 8.f)) {
      float nm = fmaxf(m, pm);
      float corr = __expf(m - nm);
      m = nm; l *= corr;
#pragma unroll
      for (int r = 0; r < 16; ++r) {
        float cr = __shfl(corr, (r & 3) + 8 * (r >> 2) + 4 * hi);
#pragma unroll
        for (int et = 0; et < 4; ++et) acc[et][r] *= cr;
      }
    }

    unsigned cpk[4][4];
    float ls = 0.f;
#pragma unroll
    for (int ts = 0; ts < 2; ++ts)
#pragma unroll
      for (int i = 0; i < 8; ++i) {
        float plo = __expf(sc[ts][2 * i] - m);
        float phi = __expf(sc[ts][2 * i + 1] - m);
        ls += plo + phi;
        cpk[ts * 2 + (i >> 2)][i & 3] = pack2bf(plo, phi);
      }
    ls += __shfl_xor(ls, 32);
    l += ls;

    short8 pa[4];
#pragma unroll
    for (int tc = 0; tc < 4; ++tc) {
      unsigned s0 = (unsigned)__shfl_xor((int)cpk[tc][0], 32);
      unsigned s1 = (unsigned)__shfl_xor((int)cpk[tc][1], 32);
      unsigned s2 = (unsigned)__shfl_xor((int)cpk[tc][2], 32);
      unsigned s3 = (unsigned)__shfl_xor((int)cpk[tc][3], 32);
      union { unsigned u[4]; short8 v; } fr;
      fr.u[0] = hi ? s2 : cpk[tc][0];
      fr.u[1] = hi ? s3 : cpk[tc][1];
      fr.u[2] = hi ? cpk[tc][2] : s0;
      fr.u[3] = hi ? cpk[tc][3] : s1;
      pa[tc] = fr.v;
    }

#pragma unroll
    for (int et = 0; et < 4; ++et) {
      const int vrow = et * 32 + l31;
      const int swz = (vrow & 7) << 4;
      const unsigned char* vr = &VL[cur][vrow * 128];
#pragma unroll
      for (int tc = 0; tc < 4; ++tc) {
        short8 vf = *(const short8*)(vr + ((tc * 32 + hi * 16) ^ swz));
        acc[et] = __builtin_amdgcn_mfma_f32_32x32x16_bf16(pa[tc], vf, acc[et], 0, 0, 0);
      }
    }
    __syncthreads();
    cur ^= 1;
  }

  if (nsplit == 2) {
    float* Ub = Upart + (size_t)kvs * (NHEAD * S_LEN) * HD;
#pragma unroll
    for (int et = 0; et < 4; ++et)
#pragma unroll
      for (int r = 0; r < 16; ++r) {
        int q = qt * 128 + wid * 32 + (r & 3) + 8 * (r >> 2) + 4 * hi;
        Ub[((size_t)h * S_LEN + q) * HD + et * 32 + l31] = acc[et][r];
      }
    if (lane < 32) {
      float* mlp = mlpart + ((size_t)kvs * (NHEAD * S_LEN) + (size_t)h * S_LEN + qrow) * 2;
      mlp[0] = m; mlp[1] = l;
    }
  } else {
    float inv = 1.0f / l;
#pragma unroll
    for (int et = 0; et < 4; ++et)
#pragma unroll
      for (int r = 0; r < 16; ++r) {
        float ir = __shfl(inv, (r & 3) + 8 * (r >> 2) + 4 * hi);
        int q = qt * 128 + wid * 32 + (r & 3) + 8 * (r >> 2) + 4 * hi;
        Ob[(size_t)q * D_MODEL + h * HD + et * 32 + l31] = f2bf(acc[et][r] * ir);
      }
  }
}

// ---------------------------------------------------------------- exact online-softmax merge of 2 KV halves
__global__ void attn_combine_kernel(const float* __restrict__ U, const float* __restrict__ ml,
                                    unsigned short* __restrict__ Ob)
{
  const int t = blockIdx.x * 256 + threadIdx.x;
  const int r = t >> 4;
  const int e0 = (t & 15) * 8;
  const float m1 = ml[(size_t)r * 2],                     l1 = ml[(size_t)r * 2 + 1];
  const float m2 = ml[((size_t)(NHEAD * S_LEN) + r) * 2], l2 = ml[((size_t)(NHEAD * S_LEN) + r) * 2 + 1];
  const float M = fmaxf(m1, m2);
  const float a1 = __expf(m1 - M), a2 = __expf(m2 - M);
  const float inv = 1.0f / (l1 * a1 + l2 * a2);
  const float* u1 = U + (size_t)r * HD + e0;
  const float* u2 = U + (size_t)(NHEAD * S_LEN) * HD + (size_t)r * HD + e0;
  floatx4 x1a = *(const floatx4*)u1, x1b = *(const floatx4*)(u1 + 4);
  floatx4 x2a = *(const floatx4*)u2, x2b = *(const floatx4*)(u2 + 4);
  const int s = r & (S_LEN - 1), hh = r >> 10;
  unsigned short* ob = Ob + (size_t)s * D_MODEL + hh * HD + e0;
  short8 o;
#pragma unroll
  for (int k = 0; k < 4; ++k) {
    o[k]     = (short)f2bf((x1a[k] * a1 + x2a[k] * a2) * inv);
    o[4 + k] = (short)f2bf((x1b[k] * a1 + x2b[k] * a2) * inv);
  }
  *(short8*)ob = o;
}

// ----------------------------------------------------------------
extern "C" void kernel_launch(void* const* d_in, const int* in_sizes, int n_in,
                              void* d_out, int out_size, void* d_ws, size_t ws_size,
                              hipStream_t stream)
{
  const float* hs   = (const float*)d_in[0];
  const float* fc   = (const float*)d_in[1];
  const float* fs   = (const float*)d_in[2];
  const float* mask = (const float*)d_in[3];
  const float* kc   = (const float*)d_in[4];
  const float* vc   = (const float*)d_in[5];
  const float* wq   = (const float*)d_in[6];
  const float* wk   = (const float*)d_in[7];
  const float* wv   = (const float*)d_in[8];
  const float* wo   = (const float*)d_in[9];

  float* y  = (float*)d_out;                       // (1024, 4096)
  float* kh = y + (size_t)S_LEN * D_MODEL;         // (8, 128, 2048)
  float* vh = kh + (size_t)NKV * HD * T_TOT;       // (8, 2048, 128)

  char* ws = (char*)d_ws;
  unsigned short* hs_b   = (unsigned short*)ws;                     // 8,388,608 B (later reused as rope'd q)
  float* qkv             = (float*)(ws + 8388608u);                 // 25,165,824 B
  unsigned short* attn_o = (unsigned short*)(ws + 8388608u);        // alias (attn runs after qkv consumers)
  unsigned short* khb    = (unsigned short*)(ws + 33554432u);       // 4,194,304 B
  unsigned short* vtb    = (unsigned short*)(ws + 37748736u);       // 4,194,304 B
  int* flag              = (int*)(ws + 41943040u);
  unsigned short* slotW  = (unsigned short*)(ws + 41943296u);       // weight bf16 slot / attn partials

  const size_t base = 41943296ull;
  const bool big = ws_size >= base + 50331648ull;        // all qkv weights at once
  const bool mid = ws_size >= base + 33554432ull;        // one weight matrix at a time
  const int nsplit = (ws_size >= base + 34078720ull) ? 2 : 1;
  float* Upart  = (float*)(ws + base);                   // 33,554,432 B (sequentially shared with slotW)
  float* mlpart = (float*)(ws + base + 33554432u);       //    524,288 B

  hipMemsetAsync(flag, 0, 4, stream);

  if (big) {
    // one launch: mask flag + hs conv + wq/wk/wv conv
    front_kernel<<<14592, 256, 0, stream>>>(mask, S_LEN * T_TOT, flag, hs, hs_b,
                                            wq, wk, wv, slotW);
    gemm_bf_kernel<<<768, 256, 0, stream>>>(hs_b, slotW, qkv, 1024, 6144, 4096, 6144, 16);
  } else if (mid) {
    mask_flag_kernel<<<256, 256, 0, stream>>>(mask, S_LEN * T_TOT, flag);
    convf2b_kernel<<<2048, 256, 0, stream>>>(hs, hs_b, S_LEN * D_MODEL / 8);
    convf2b_kernel<<<2048, 256, 0, stream>>>(wk, slotW, NKV * HD * D_MODEL / 8);
    convf2b_kernel<<<2048, 256, 0, stream>>>(wv, slotW + (size_t)1024 * 4096, NKV * HD * D_MODEL / 8);
    gemm_bf_kernel<<<256, 256, 0, stream>>>(hs_b, slotW, qkv + 4096, 1024, 2048, 4096, 6144, 16);
    convf2b_kernel<<<2048, 256, 0, stream>>>(wq, slotW, NHEAD * HD * D_MODEL / 8);
    gemm_bf_kernel<<<512, 256, 0, stream>>>(hs_b, slotW, qkv, 1024, 4096, 4096, 6144, 16);
  } else {
    mask_flag_kernel<<<256, 256, 0, stream>>>(mask, S_LEN * T_TOT, flag);
    convf2b_kernel<<<2048, 256, 0, stream>>>(hs, hs_b, S_LEN * D_MODEL / 8);
    gemm_kernel<<<384, 256, 0, stream>>>(hs_b, wq, wk, wv, 4096, 5120, qkv, 1024, 6144, 4096, 8);
  }

  // one launch: rope_q + K prep + V prep
  prep_all_kernel<<<1664, 256, 0, stream>>>(qkv, fc, fs, kc, vc, hs_b, kh, khb, vh, vtb);

  attn_kernel<<<256 * nsplit, 256, 0, stream>>>(hs_b, khb, vtb, mask, flag, attn_o,
                                                Upart, mlpart, nsplit);
  if (nsplit == 2)
    attn_combine_kernel<<<2048, 256, 0, stream>>>(Upart, mlpart, attn_o);

  if (mid) {  // big implies mid
    convf2b_kernel<<<2048, 256, 0, stream>>>(wo, slotW, D_MODEL * D_MODEL / 8);
    gemm_bf_kernel<<<512, 256, 0, stream>>>(attn_o, slotW, y, 1024, 4096, 4096, 4096, 16);
  } else {
    gemm_kernel<<<256, 256, 0, stream>>>(attn_o, wo, wo, wo, 1 << 29, 1 << 29, y, 1024, 4096, 4096, 8);
  }
}